// Round 12
// baseline (418.181 us; speedup 1.0000x reference)
//
#include <hip/hip_runtime.h>

// Problem constants
#define BATCH 16
#define CH 64          // EMBEDDING_DIM
#define HW 4096        // 64*64
#define NPIX 65536     // BATCH*HW
#define KCODES 512
#define DDIM 64
#define NELEM 4194304  // NPIX*CH

// d_out layout (float32): [z_q_st: NELEM][loss: 1][ppl: 1][indices: NPIX]
#define OUT_LOSS 4194304
#define OUT_PPL  4194305
#define OUT_IDX  4194306

// bf16 gap-error: rms ~4e-5 => 2.2e-4 is ~5.5 sigma; covers np fp32 quantization (7.6e-6)
#define MARGIN 2.2e-4f

typedef short bf16x8 __attribute__((ext_vector_type(8)));
typedef float f32x4  __attribute__((ext_vector_type(4)));

__device__ __forceinline__ float rnd(float s) {   // block fp-contract (numpy-exact squares)
    asm volatile("" : "+v"(s));
    return s;
}
__device__ __forceinline__ short f2bf(float f) {  // RNE fp32->bf16
    unsigned u = __builtin_bit_cast(unsigned, f);
    unsigned r = (u + 0x7fffu + ((u >> 16) & 1u)) >> 16;
    return (short)r;
}

// -------------------- prep: e2 + fragment-ordered bf16 codebook + channel-major fp32 ---
// Bh packing: entry = tn*128 + chunk*64 + lane, lane=(q<<4)|i:
//   code = tn*16+i, k = chunk*32 + q*8 + j (j=0..7), 16B/entry.  (layout HW-verified R4)
// ET packing (for fused refine): ET[c*512 + k] = emb[k*64 + c]  (channel-major, so
// thread t reading code t is coalesced — R7/R8 lesson: row-major reads were 64
// cache lines per instruction).
__global__ void k_prep(const float* __restrict__ emb, float* __restrict__ e2,
                       bf16x8* __restrict__ Bh, float4* __restrict__ ET4) {
    int gid = blockIdx.x * 256 + threadIdx.x;
    if (gid < 4096) {
        int tn = gid >> 7, rem = gid & 127;
        int chunk = (rem >> 6) & 1, q = (rem >> 4) & 3, i = rem & 15;
        int code = tn * 16 + i;
        const float* src = emb + code * DDIM + chunk * 32 + q * 8;
        bf16x8 h;
        #pragma unroll
        for (int j = 0; j < 8; ++j) h[j] = f2bf(src[j]);
        Bh[gid] = h;
    } else if (gid < 4608) {
        int k = gid - 4096;
        const float* row = emb + k * DDIM;
        float r[8];
        #pragma unroll
        for (int j = 0; j < 8; ++j) { float v = row[j]; r[j] = rnd(v * v); }
        #pragma unroll
        for (int m = 1; m < 8; ++m)
            #pragma unroll
            for (int j = 0; j < 8; ++j) { float v = row[8 * m + j]; r[j] += rnd(v * v); }
        e2[k] = ((r[0] + r[1]) + (r[2] + r[3])) + ((r[4] + r[5]) + (r[6] + r[7]));
    } else if (gid < 12800) {
        int pid = gid - 4608;            // 8192 float4 entries
        int c = pid >> 7, kg = pid & 127;
        float4 v;
        v.x = emb[(kg * 4 + 0) * DDIM + c];
        v.y = emb[(kg * 4 + 1) * DDIM + c];
        v.z = emb[(kg * 4 + 2) * DDIM + c];
        v.w = emb[(kg * 4 + 3) * DDIM + c];
        ET4[c * 128 + kg] = v;
    }
}

// -------------------- fully fused: distance/argmin + numpy-exact refine + epilogue ----
// 512 thr = 8 waves x 16 px = 128 px/block. Grid 512 -> 2 blocks/CU, all resident.
// Full 64 KB bf16 codebook staged into LDS once. Flagged near-ties re-checked
// IN-BLOCK (one code per thread, numpy-fp32-exact) before the epilogue, so
// z_q_st / loss / counts / indices are written correct the first time.
__global__ __launch_bounds__(512, 4) void k_dist(
        const float* __restrict__ z_e, const float* __restrict__ emb,
        const bf16x8* __restrict__ Bh, const float* __restrict__ e2g,
        const float* __restrict__ ET,
        int* __restrict__ counts, float* __restrict__ slots,
        float* __restrict__ out) {
    __shared__ bf16x8 Bs[4096];      // 64 KB: full codebook, fragment order
    __shared__ float e2s[512];
    __shared__ int   hist[512];
    __shared__ int   best_px[128];   // final code per local px
    __shared__ int   flist[128];     // local px of flagged near-ties
    __shared__ float xflag[16][64];  // staged x-vectors for one refine chunk (4 KB)
    __shared__ float wd[16][8];      // per-wave reduced distance
    __shared__ int   wi[16][8];      // per-wave reduced index
    __shared__ int   fcnt;

    int t = threadIdx.x;
    int pxbase = blockIdx.x * 128;
    int batch = pxbase >> 12;
    int p0 = pxbase & 4095;
    const float* zb = z_e + (size_t)batch * (CH * HW) + p0;

    // issue the 8 B-stage loads first so they're in flight during A-loads
    bf16x8 rb[8];
    #pragma unroll
    for (int i = 0; i < 8; ++i) rb[i] = Bh[i * 512 + t];

    hist[t] = 0;
    e2s[t] = e2g[t];
    if (t == 0) fcnt = 0;

    int w = t >> 6, lane = t & 63, col = lane & 15, quad = lane >> 4;
    int px = w * 16 + col;

    // A-frags direct from global: px = w*16+col, k = chunk*32 + quad*8 + j
    bf16x8 a0, a1;
    #pragma unroll
    for (int j = 0; j < 8; ++j) {
        a0[j] = f2bf(zb[(quad * 8 + j) * HW + px]);
        a1[j] = f2bf(zb[(32 + quad * 8 + j) * HW + px]);
    }

    // commit B to LDS; barrier #1
    #pragma unroll
    for (int i = 0; i < 8; ++i) Bs[i * 512 + t] = rb[i];
    __syncthreads();

    float m1[4], m2[4];
    int   i1[4];
    #pragma unroll
    for (int r = 0; r < 4; ++r) { m1[r] = 1e30f; m2[r] = 1e30f; i1[r] = 0; }

    // barrier-free N loop: pure ds_read_b128 + MFMA + select
    #pragma unroll 4
    for (int tn = 0; tn < 32; ++tn) {
        bf16x8 c0 = Bs[tn * 128 + lane];
        bf16x8 c1 = Bs[tn * 128 + 64 + lane];
        float e2v = e2s[tn * 16 + col];
        int n = tn * 16 + col;
        f32x4 acc = {0.f, 0.f, 0.f, 0.f};
        acc = __builtin_amdgcn_mfma_f32_16x16x32_bf16(a0, c0, acc, 0, 0, 0);
        acc = __builtin_amdgcn_mfma_f32_16x16x32_bf16(a1, c1, acc, 0, 0, 0);
        #pragma unroll
        for (int r = 0; r < 4; ++r) {
            float d = fmaf(-2.0f, acc[r], e2v);
            if (d < m1[r])      { m2[r] = m1[r]; m1[r] = d; i1[r] = n; }
            else if (d < m2[r]) { m2[r] = d; }
        }
    }

    // merge the 16 cols (xor butterfly -> every lane holds result for px quad*4+r)
    #pragma unroll
    for (int off = 1; off < 16; off <<= 1) {
        #pragma unroll
        for (int r = 0; r < 4; ++r) {
            float om1 = __shfl_xor(m1[r], off);
            float om2 = __shfl_xor(m2[r], off);
            int   oi  = __shfl_xor(i1[r], off);
            if (om1 < m1[r] || (om1 == m1[r] && oi < i1[r])) {
                m2[r] = fminf(m1[r], om2);
                m1[r] = om1;
                i1[r] = oi;
            } else {
                m2[r] = fminf(m2[r], om1);
            }
        }
    }

    // provisional best + flag list (LDS only)
    if (col == 0) {
        #pragma unroll
        for (int r = 0; r < 4; ++r) {
            int lp = w * 16 + quad * 4 + r;
            best_px[lp] = i1[r];
            if (m2[r] - m1[r] < MARGIN) {
                int pos = atomicAdd(&fcnt, 1);
                flist[pos] = lp;
            }
        }
    }
    __syncthreads();   // barrier #2: best_px/flist/fcnt visible

    // ---- fused numpy-fp32-exact refine: one code per thread, chunks of 16 flags ----
    int nf = fcnt;     // block-uniform
    for (int base = 0; base < nf; base += 16) {
        int nc = min(16, nf - base);
        // stage x-vectors (L1-hot: this block already read these px)
        for (int i = t; i < nc * 64; i += 512) {
            int f = i >> 6, c = i & 63;
            xflag[f][c] = zb[c * HW + flist[base + f]];
        }
        __syncthreads();
        for (int f = 0; f < nc; ++f) {
            const float* xr = xflag[f];
            // numpy pairwise ||x||^2 (8 accumulators + tree) — broadcast LDS reads
            float r[8];
            #pragma unroll
            for (int jj = 0; jj < 8; ++jj) { float v = xr[jj]; r[jj] = rnd(v * v); }
            #pragma unroll
            for (int mm = 1; mm < 8; ++mm)
                #pragma unroll
                for (int jj = 0; jj < 8; ++jj) { float v = xr[8 * mm + jj]; r[jj] += rnd(v * v); }
            float x2 = ((r[0] + r[1]) + (r[2] + r[3])) + ((r[4] + r[5]) + (r[6] + r[7]));

            // fp64 dot for code t (verified 4-accumulator pattern); ET coalesced
            double d0 = 0.0, d1 = 0.0, d2 = 0.0, d3 = 0.0;
            #pragma unroll
            for (int c4 = 0; c4 < 16; ++c4) {
                float4 xq = *(const float4*)&xr[c4 * 4];      // broadcast
                d0 = fma((double)xq.x, (double)ET[(c4 * 4 + 0) * 512 + t], d0);
                d1 = fma((double)xq.y, (double)ET[(c4 * 4 + 1) * 512 + t], d1);
                d2 = fma((double)xq.z, (double)ET[(c4 * 4 + 2) * 512 + t], d2);
                d3 = fma((double)xq.w, (double)ET[(c4 * 4 + 3) * 512 + t], d3);
            }
            float dotf = (float)((d0 + d1) + (d2 + d3));  // ~= sgemm dot
            float tt = x2 + e2s[t];                       // np fp32 add
            float d = tt - 2.0f * dotf;                   // np fp32 sub
            // wave lex-min (d, then smaller code = np first occurrence)
            float bd = d; int bi = t;
            #pragma unroll
            for (int off = 32; off; off >>= 1) {
                float od = __shfl_down(bd, off);
                int   oi = __shfl_down(bi, off);
                if (od < bd || (od == bd && oi < bi)) { bd = od; bi = oi; }
            }
            if (lane == 0) { wd[f][w] = bd; wi[f][w] = bi; }
        }
        __syncthreads();
        if (t < nc) {   // finalize flag base+t: scan the 8 wave results in order
            float bd = wd[t][0]; int bi = wi[t][0];
            #pragma unroll
            for (int ww = 1; ww < 8; ++ww) {
                float od = wd[t][ww]; int oi = wi[t][ww];
                if (od < bd || (od == bd && oi < bi)) { bd = od; bi = oi; }
            }
            best_px[flist[base + t]] = bi;
        }
        __syncthreads();
    }

    // indices output + histogram from FINAL assignments
    if (t < 128) {
        int bi = best_px[t];
        out[OUT_IDX + pxbase + t] = (float)bi;
        atomicAdd(&hist[bi], 1);
    }

    // epilogue: z_q_st + loss partial from FINAL assignments (z_e is L1-hot)
    int q4 = lane & 3;
    int bidx[4];
    #pragma unroll
    for (int j = 0; j < 4; ++j) bidx[j] = best_px[w * 16 + q4 * 4 + j];
    const float* zw = zb + w * 16;
    float* ow = out + (size_t)batch * (CH * HW) + p0 + w * 16;
    float lsum = 0.0f;
    #pragma unroll
    for (int it = 0; it < 4; ++it) {
        int c = it * 16 + (lane >> 2);
        float4 ze = *(const float4*)(zw + c * HW + q4 * 4);
        float d0 = emb[bidx[0] * DDIM + c] - ze.x;
        float d1 = emb[bidx[1] * DDIM + c] - ze.y;
        float d2 = emb[bidx[2] * DDIM + c] - ze.z;
        float d3 = emb[bidx[3] * DDIM + c] - ze.w;
        float4 o = {ze.x + d0, ze.y + d1, ze.z + d2, ze.w + d3};
        *(float4*)(ow + c * HW + q4 * 4) = o;
        lsum = lsum + d0 * d0 + d1 * d1 + d2 * d2 + d3 * d3;
    }
    #pragma unroll
    for (int off = 32; off; off >>= 1) lsum += __shfl_down(lsum, off);
    if (lane == 0) atomicAdd(&slots[((blockIdx.x * 8 + w) & 63) * 16], lsum);

    // final barrier, then flush histogram
    __syncthreads();
    int v0 = hist[t];
    if (v0) atomicAdd(&counts[t], v0);
}

// -------------------- final scalars: loss, perplexity --------------------
__global__ void k_final(const int* __restrict__ counts,
                        const float* __restrict__ slots,
                        float* __restrict__ out) {
    int t = threadIdx.x;  // 512 threads, 1 block
    float cnt = (float)counts[t];
    float pb = cnt * (1.0f / 65536.0f);
    float term = pb * logf(pb + 1e-10f);
    #pragma unroll
    for (int off = 32; off; off >>= 1) term += __shfl_down(term, off);
    __shared__ float ls[8];
    __shared__ float lsum;
    int lane = t & 63, w = t >> 6;
    if (lane == 0) ls[w] = term;
    if (w == 0) {                               // wave 0 reduces the 64 loss slots
        float s2 = slots[lane * 16];
        #pragma unroll
        for (int off = 32; off; off >>= 1) s2 += __shfl_down(s2, off);
        if (lane == 0) lsum = s2;
    }
    __syncthreads();
    if (t == 0) {
        float s = 0.0f;
        #pragma unroll
        for (int i = 0; i < 8; ++i) s += ls[i];
        out[OUT_PPL]  = expf(-s);
        out[OUT_LOSS] = 0.25f * (lsum / (float)NELEM);
    }
}

extern "C" void kernel_launch(void* const* d_in, const int* in_sizes, int n_in,
                              void* d_out, int out_size, void* d_ws, size_t ws_size,
                              hipStream_t stream) {
    const float* z_e = (const float*)d_in[0];
    const float* emb = (const float*)d_in[1];
    float* out = (float*)d_out;
    char* ws = (char*)d_ws;

    // ws layout
    float*  e2     = (float*)(ws);            // 512 floats   [0, 2048)
    int*    counts = (int*)(ws + 2048);       // 512 ints     [2048, 4096)
    float*  slots  = (float*)(ws + 4096);     // 64 x 16 floats [4096, 8192)
    bf16x8* Bh     = (bf16x8*)(ws + 8192);    // 4096 x 16 B = 64 KB [8192, 73728)
    float*  ET     = (float*)(ws + 73728);    // 512x64 floats = 128 KB [73728, 204800)

    // zero counts + slots (ws is poisoned 0xAA before every timed launch)
    hipMemsetAsync(ws + 2048, 0, 8192 - 2048, stream);

    k_prep<<<50, 256, 0, stream>>>(emb, e2, Bh, (float4*)ET);
    k_dist<<<NPIX / 128, 512, 0, stream>>>(z_e, emb, Bh, e2, ET, counts, slots, out);
    k_final<<<1, 512, 0, stream>>>(counts, slots, out);
}

// Round 13
// 139.018 us; speedup vs baseline: 3.0081x; 3.0081x over previous
//
#include <hip/hip_runtime.h>

// Problem constants
#define BATCH 16
#define CH 64          // EMBEDDING_DIM
#define HW 4096        // 64*64
#define NPIX 65536     // BATCH*HW
#define KCODES 512
#define DDIM 64
#define NELEM 4194304  // NPIX*CH

// d_out layout (float32): [z_q_st: NELEM][loss: 1][ppl: 1][indices: NPIX]
#define OUT_LOSS 4194304
#define OUT_PPL  4194305
#define OUT_IDX  4194306

// bf16 gap-error: rms ~4e-5 => 2.2e-4 is ~5.5 sigma; covers np fp32 quantization (7.6e-6)
#define MARGIN 2.2e-4f

typedef short bf16x8 __attribute__((ext_vector_type(8)));
typedef float f32x4  __attribute__((ext_vector_type(4)));

__device__ __forceinline__ float rnd(float s) {   // block fp-contract (numpy-exact squares)
    asm volatile("" : "+v"(s));
    return s;
}
__device__ __forceinline__ short f2bf(float f) {  // RNE fp32->bf16
    unsigned u = __builtin_bit_cast(unsigned, f);
    unsigned r = (u + 0x7fffu + ((u >> 16) & 1u)) >> 16;
    return (short)r;
}
// direct global->LDS DMA, 16B/lane (dest must be wave-uniform base + lane*16)
__device__ __forceinline__ void gl_lds16(const void* g, void* l) {
    __builtin_amdgcn_global_load_lds(
        (const __attribute__((address_space(1))) unsigned*)g,
        (__attribute__((address_space(3))) unsigned*)l, 16, 0, 0);
}

// -------------------- prep: e2 + fragment-ordered bf16 codebook + coalesced fp32 transpose ---
// Bh packing: entry = tn*128 + chunk*64 + lane, lane=(q<<4)|i:
//   code = tn*16+i, k = chunk*32 + q*8 + j (j=0..7), 16B/entry.  (layout HW-verified R4)
// P4 packing (for refine): P4[(kk*16+c4)*64 + lane] = emb[lane*8+kk][c4*4..+3]
__global__ void k_prep(const float* __restrict__ emb, float* __restrict__ e2,
                       bf16x8* __restrict__ Bh, float4* __restrict__ P4) {
    int gid = blockIdx.x * 256 + threadIdx.x;
    if (gid < 4096) {
        int tn = gid >> 7, rem = gid & 127;
        int chunk = (rem >> 6) & 1, q = (rem >> 4) & 3, i = rem & 15;
        int code = tn * 16 + i;
        const float* src = emb + code * DDIM + chunk * 32 + q * 8;
        bf16x8 h;
        #pragma unroll
        for (int j = 0; j < 8; ++j) h[j] = f2bf(src[j]);
        Bh[gid] = h;
    } else if (gid < 4608) {
        int k = gid - 4096;
        const float* row = emb + k * DDIM;
        float r[8];
        #pragma unroll
        for (int j = 0; j < 8; ++j) { float v = row[j]; r[j] = rnd(v * v); }
        #pragma unroll
        for (int m = 1; m < 8; ++m)
            #pragma unroll
            for (int j = 0; j < 8; ++j) { float v = row[8 * m + j]; r[j] += rnd(v * v); }
        e2[k] = ((r[0] + r[1]) + (r[2] + r[3])) + ((r[4] + r[5]) + (r[6] + r[7]));
    } else if (gid < 12800) {
        int pid = gid - 4608;            // 8192 entries
        int kk = pid >> 10, c4 = (pid >> 6) & 15, lane = pid & 63;
        int code = lane * 8 + kk;
        P4[pid] = *(const float4*)(emb + code * DDIM + c4 * 4);
    }
}

// -------------------- fused distance/argmin + epilogue kernel --------------------
// 512 thr = 8 waves x 16 px = 128 px/block. Grid 512 -> 2 blocks/CU, all resident.
// Full 64 KB bf16 codebook staged into LDS ONCE via global_load_lds DMA (no VGPR
// round-trip — R12's rb[8] chain contributed to spill). Two barriers per block.
__global__ __launch_bounds__(512, 4) void k_dist(
        const float* __restrict__ z_e, const float* __restrict__ emb,
        const bf16x8* __restrict__ Bh, const float* __restrict__ e2g,
        int* __restrict__ idx, int* __restrict__ glist, int* __restrict__ nflag,
        int* __restrict__ counts, float* __restrict__ slots,
        float* __restrict__ out) {
    __shared__ bf16x8 Bs[4096];      // 64 KB: full codebook, fragment order
    __shared__ float e2s[512];
    __shared__ int   hist[512];
    __shared__ int   flist[128];
    __shared__ int   fcnt, fbase;

    int t = threadIdx.x;
    int pxbase = blockIdx.x * 128;
    int batch = pxbase >> 12;
    int p0 = pxbase & 4095;
    const float* zb = z_e + (size_t)batch * (CH * HW) + p0;

    // B-stage: fire 8 async 16B DMAs (in flight during A-loads below)
    #pragma unroll
    for (int i = 0; i < 8; ++i) gl_lds16(Bh + i * 512 + t, Bs + i * 512 + t);

    hist[t] = 0;
    e2s[t] = e2g[t];
    if (t == 0) fcnt = 0;

    int w = t >> 6, lane = t & 63, col = lane & 15, quad = lane >> 4;
    int px = w * 16 + col;

    // A-frags direct from global: px = w*16+col, k = chunk*32 + quad*8 + j
    bf16x8 a0, a1;
    #pragma unroll
    for (int j = 0; j < 8; ++j) {
        a0[j] = f2bf(zb[(quad * 8 + j) * HW + px]);
        a1[j] = f2bf(zb[(32 + quad * 8 + j) * HW + px]);
    }
    __syncthreads();   // barrier #1 (drains the DMA vmcnt)

    float m1[4], m2[4];
    int   i1[4];
    #pragma unroll
    for (int r = 0; r < 4; ++r) { m1[r] = 1e30f; m2[r] = 1e30f; i1[r] = 0; }

    // barrier-free N loop: pure ds_read_b128 + MFMA + select
    #pragma unroll 4
    for (int tn = 0; tn < 32; ++tn) {
        bf16x8 c0 = Bs[tn * 128 + lane];
        bf16x8 c1 = Bs[tn * 128 + 64 + lane];
        float e2v = e2s[tn * 16 + col];
        int n = tn * 16 + col;
        f32x4 acc = {0.f, 0.f, 0.f, 0.f};
        acc = __builtin_amdgcn_mfma_f32_16x16x32_bf16(a0, c0, acc, 0, 0, 0);
        acc = __builtin_amdgcn_mfma_f32_16x16x32_bf16(a1, c1, acc, 0, 0, 0);
        #pragma unroll
        for (int r = 0; r < 4; ++r) {
            float d = fmaf(-2.0f, acc[r], e2v);
            if (d < m1[r])      { m2[r] = m1[r]; m1[r] = d; i1[r] = n; }
            else if (d < m2[r]) { m2[r] = d; }
        }
    }

    // merge the 16 cols (xor butterfly -> every lane holds result for px quad*4+r)
    #pragma unroll
    for (int off = 1; off < 16; off <<= 1) {
        #pragma unroll
        for (int r = 0; r < 4; ++r) {
            float om1 = __shfl_xor(m1[r], off);
            float om2 = __shfl_xor(m2[r], off);
            int   oi  = __shfl_xor(i1[r], off);
            if (om1 < m1[r] || (om1 == m1[r] && oi < i1[r])) {
                m2[r] = fminf(m1[r], om2);
                m1[r] = om1;
                i1[r] = oi;
            } else {
                m2[r] = fminf(m2[r], om1);
            }
        }
    }

    // per-pixel outputs: idx, out-idx, LDS histogram + LDS flag list (no global atomics)
    if (col == 0) {
        #pragma unroll
        for (int r = 0; r < 4; ++r) {
            int g = pxbase + w * 16 + quad * 4 + r;
            idx[g] = i1[r];
            out[OUT_IDX + g] = (float)i1[r];
            atomicAdd(&hist[i1[r]], 1);
            if (m2[r] - m1[r] < MARGIN) {
                int pos = atomicAdd(&fcnt, 1);   // LDS atomic
                flist[pos] = g;
            }
        }
    }

    // fused epilogue: z_q_st for this wave's 16 px (z_e is L1/L3-hot), + loss partial
    int q4 = lane & 3;
    int bidx[4];
    #pragma unroll
    for (int j = 0; j < 4; ++j) bidx[j] = __shfl(i1[j], q4 << 4);  // best for px q4*4+j
    const float* zw = zb + w * 16;
    float* ow = out + (size_t)batch * (CH * HW) + p0 + w * 16;
    float lsum = 0.0f;
    #pragma unroll
    for (int it = 0; it < 4; ++it) {
        int c = it * 16 + (lane >> 2);
        float4 ze = *(const float4*)(zw + c * HW + q4 * 4);
        float d0 = emb[bidx[0] * DDIM + c] - ze.x;
        float d1 = emb[bidx[1] * DDIM + c] - ze.y;
        float d2 = emb[bidx[2] * DDIM + c] - ze.z;
        float d3 = emb[bidx[3] * DDIM + c] - ze.w;
        float4 o = {ze.x + d0, ze.y + d1, ze.z + d2, ze.w + d3};
        *(float4*)(ow + c * HW + q4 * 4) = o;
        lsum = lsum + d0 * d0 + d1 * d1 + d2 * d2 + d3 * d3;
    }
    #pragma unroll
    for (int off = 32; off; off >>= 1) lsum += __shfl_down(lsum, off);
    if (lane == 0) atomicAdd(&slots[((blockIdx.x * 8 + w) & 63) * 16], lsum);

    // barrier #2, then flush histogram + flag list (one returning atomic per block)
    __syncthreads();
    int v0 = hist[t];
    if (v0) atomicAdd(&counts[t], v0);
    if (t == 0) fbase = atomicAdd(nflag, fcnt);
    __syncthreads();
    if (t < fcnt) glist[fbase + t] = flist[t];
}

// -------------------- refine: full codebook in LDS, numpy-fp32-exact re-argmin ------
// Full 128 KB fp32 transposed codebook staged ONCE per block via global_load_lds
// (R12 lesson: streaming it per-flag from L2 = 268 MB fetch = 350 us). One barrier,
// then each wave grid-strides flags barrier-free. Numerics identical to the
// R9-R11-verified path.  __launch_bounds__(256) is LOAD-BEARING (R5: VGPR cap 64
// -> spill -> 90 MB scratch traffic).
__global__ __launch_bounds__(256) void k_refine(
        const float* __restrict__ z_e, const float* __restrict__ emb,
        const float* __restrict__ e2, const float4* __restrict__ P4,
        const int* __restrict__ glist, const int* __restrict__ nflag,
        int* __restrict__ idx, int* __restrict__ counts,
        float* __restrict__ slots, float* __restrict__ out) {
    __shared__ float4 Ps[8192];      // 128 KB: full transposed codebook
    __shared__ float  xs[4][64];     // one x-vector slot per wave

    int t = threadIdx.x;
    int w = t >> 6, lane = t & 63;
    int n = nflag[0];
    if (blockIdx.x >= n) return;     // block-uniform early exit (handles n==0)

    #pragma unroll
    for (int i = 0; i < 32; ++i) gl_lds16(P4 + i * 256 + t, Ps + i * 256 + t);
    __syncthreads();                 // the only barrier (drains DMA)

    // per-lane e2 for codes lane*8..+7 (coalesced float4 pair)
    float4 ea = ((const float4*)e2)[lane * 2];
    float4 eb = ((const float4*)e2)[lane * 2 + 1];
    float e2v[8] = {ea.x, ea.y, ea.z, ea.w, eb.x, eb.y, eb.z, eb.w};

    int wid = blockIdx.x * 4 + w;
    for (int j = wid; j < n; j += 1024) {
        int g = glist[j];                 // wave-uniform scalar load
        int b = g >> 12, p = g & 4095;
        xs[w][lane] = z_e[(size_t)b * (CH * HW) + (size_t)lane * HW + p];
        __threadfence_block();            // wave-lockstep LDS visibility

        const float* xr = xs[w];
        // numpy pairwise ||x||^2 (8 accumulators + tree), broadcast LDS reads
        float r[8];
        #pragma unroll
        for (int jj = 0; jj < 8; ++jj) { float v = xr[jj]; r[jj] = rnd(v * v); }
        #pragma unroll
        for (int mm = 1; mm < 8; ++mm)
            #pragma unroll
            for (int jj = 0; jj < 8; ++jj) { float v = xr[8 * mm + jj]; r[jj] += rnd(v * v); }
        float x2 = ((r[0] + r[1]) + (r[2] + r[3])) + ((r[4] + r[5]) + (r[6] + r[7]));

        float bestd = INFINITY;
        int besti = 1 << 30;
        #pragma unroll
        for (int kk = 0; kk < 8; ++kk) {
            double d0 = 0.0, d1 = 0.0, d2 = 0.0, d3 = 0.0;
            #pragma unroll
            for (int c4 = 0; c4 < 16; ++c4) {
                float4 xq = *(const float4*)&xr[c4 * 4];         // broadcast
                float4 ev = Ps[(kk * 16 + c4) * 64 + lane];      // per-lane, conflict-free
                d0 = fma((double)xq.x, (double)ev.x, d0);
                d1 = fma((double)xq.y, (double)ev.y, d1);
                d2 = fma((double)xq.z, (double)ev.z, d2);
                d3 = fma((double)xq.w, (double)ev.w, d3);
            }
            float dotf = (float)((d0 + d1) + (d2 + d3));  // ~= sgemm dot
            float tt = x2 + e2v[kk];                      // np fp32 add
            float d = tt - 2.0f * dotf;                   // np fp32 sub
            if (d < bestd) { bestd = d; besti = lane * 8 + kk; }
        }
        #pragma unroll
        for (int off = 32; off; off >>= 1) {
            float od = __shfl_down(bestd, off);
            int   oi = __shfl_down(besti, off);
            if (od < bestd || (od == bestd && oi < besti)) { bestd = od; besti = oi; }
        }
        besti = __shfl(besti, 0);

        int old = idx[g];
        if (besti != old) {
            // patch z_q_st row (lane c = channel c), loss delta, counts, index
            float xc = xr[lane];
            float qn = emb[besti * DDIM + lane];
            float qo = emb[old * DDIM + lane];
            float dn = qn - xc, dold = qo - xc;
            out[(size_t)b * (CH * HW) + (size_t)lane * HW + p] = xc + dn;
            float delta = dn * dn - dold * dold;
            #pragma unroll
            for (int off = 32; off; off >>= 1) delta += __shfl_down(delta, off);
            if (lane == 0) {
                atomicAdd(&slots[(wid & 63) * 16], delta);
                atomicAdd(&counts[old], -1);
                atomicAdd(&counts[besti], 1);
                idx[g] = besti;
                out[OUT_IDX + g] = (float)besti;
            }
        }
    }
}

// -------------------- final scalars: loss, perplexity --------------------
__global__ void k_final(const int* __restrict__ counts,
                        const float* __restrict__ slots,
                        float* __restrict__ out) {
    int t = threadIdx.x;  // 512 threads, 1 block
    float cnt = (float)counts[t];
    float pb = cnt * (1.0f / 65536.0f);
    float term = pb * logf(pb + 1e-10f);
    #pragma unroll
    for (int off = 32; off; off >>= 1) term += __shfl_down(term, off);
    __shared__ float ls[8];
    __shared__ float lsum;
    int lane = t & 63, w = t >> 6;
    if (lane == 0) ls[w] = term;
    if (w == 0) {                               // wave 0 reduces the 64 loss slots
        float s2 = slots[lane * 16];
        #pragma unroll
        for (int off = 32; off; off >>= 1) s2 += __shfl_down(s2, off);
        if (lane == 0) lsum = s2;
    }
    __syncthreads();
    if (t == 0) {
        float s = 0.0f;
        #pragma unroll
        for (int i = 0; i < 8; ++i) s += ls[i];
        out[OUT_PPL]  = expf(-s);
        out[OUT_LOSS] = 0.25f * (lsum / (float)NELEM);
    }
}

extern "C" void kernel_launch(void* const* d_in, const int* in_sizes, int n_in,
                              void* d_out, int out_size, void* d_ws, size_t ws_size,
                              hipStream_t stream) {
    const float* z_e = (const float*)d_in[0];
    const float* emb = (const float*)d_in[1];
    float* out = (float*)d_out;
    char* ws = (char*)d_ws;

    // ws layout
    int*    idx    = (int*)(ws);              // 65536 ints   [0, 262144)
    int*    glist  = (int*)(ws + 262144);     // 65536 ints   [262144, 524288)
    float*  e2     = (float*)(ws + 524288);   // 512 floats   [524288, 526336)
    int*    nflag  = (int*)(ws + 526336);     // 1 int (+pad) [526336, 526400)
    int*    counts = (int*)(ws + 526400);     // 512 ints     [526400, 528448)
    float*  slots  = (float*)(ws + 528448);   // 64 x 16 floats [528448, 532544)
    bf16x8* Bh     = (bf16x8*)(ws + 532544);  // 4096 x 16 B = 64 KB
    float4* P4     = (float4*)(ws + 598080);  // 8192 x 16 B = 128 KB [598080, 729152)

    // zero nflag + counts + slots (ws is poisoned 0xAA before every timed launch)
    hipMemsetAsync(ws + 526336, 0, 532544 - 526336, stream);

    k_prep<<<50, 256, 0, stream>>>(emb, e2, Bh, P4);
    k_dist<<<NPIX / 128, 512, 0, stream>>>(z_e, emb, Bh, e2, idx, glist, nflag, counts, slots, out);
    k_refine<<<256, 256, 0, stream>>>(z_e, emb, e2, P4, glist, nflag, idx, counts, slots, out);
    k_final<<<1, 512, 0, stream>>>(counts, slots, out);
}

// Round 14
// 128.628 us; speedup vs baseline: 3.2511x; 1.0808x over previous
//
#include <hip/hip_runtime.h>

// Problem constants
#define BATCH 16
#define CH 64          // EMBEDDING_DIM
#define HW 4096        // 64*64
#define NPIX 65536     // BATCH*HW
#define KCODES 512
#define DDIM 64
#define NELEM 4194304  // NPIX*CH

// d_out layout (float32): [z_q_st: NELEM][loss: 1][ppl: 1][indices: NPIX]
#define OUT_LOSS 4194304
#define OUT_PPL  4194305
#define OUT_IDX  4194306

// bf16 gap-error: rms ~4e-5 => 2.2e-4 is ~5.5 sigma; covers np fp32 quantization (7.6e-6)
#define MARGIN 2.2e-4f

typedef short bf16x8 __attribute__((ext_vector_type(8)));
typedef float f32x4  __attribute__((ext_vector_type(4)));

__device__ __forceinline__ float rnd(float s) {   // block fp-contract (numpy-exact squares)
    asm volatile("" : "+v"(s));
    return s;
}
__device__ __forceinline__ short f2bf(float f) {  // RNE fp32->bf16
    unsigned u = __builtin_bit_cast(unsigned, f);
    unsigned r = (u + 0x7fffu + ((u >> 16) & 1u)) >> 16;
    return (short)r;
}
// direct global->LDS DMA, 16B/lane (dest must be wave-uniform base + lane*16)
__device__ __forceinline__ void gl_lds16(const void* g, void* l) {
    __builtin_amdgcn_global_load_lds(
        (const __attribute__((address_space(1))) unsigned*)g,
        (__attribute__((address_space(3))) unsigned*)l, 16, 0, 0);
}

// -------------------- prep: e2 + fragment-ordered bf16 codebook + coalesced fp32 transpose ---
// Bh packing: entry = tn*128 + chunk*64 + lane, lane=(q<<4)|i:
//   code = tn*16+i, k = chunk*32 + q*8 + j (j=0..7), 16B/entry.  (layout HW-verified R4)
// P4 packing (for refine): P4[(kk*16+c4)*64 + lane] = emb[lane*8+kk][c4*4..+3]
__global__ void k_prep(const float* __restrict__ emb, float* __restrict__ e2,
                       bf16x8* __restrict__ Bh, float4* __restrict__ P4) {
    int gid = blockIdx.x * 256 + threadIdx.x;
    if (gid < 4096) {
        int tn = gid >> 7, rem = gid & 127;
        int chunk = (rem >> 6) & 1, q = (rem >> 4) & 3, i = rem & 15;
        int code = tn * 16 + i;
        const float* src = emb + code * DDIM + chunk * 32 + q * 8;
        bf16x8 h;
        #pragma unroll
        for (int j = 0; j < 8; ++j) h[j] = f2bf(src[j]);
        Bh[gid] = h;
    } else if (gid < 4608) {
        int k = gid - 4096;
        const float* row = emb + k * DDIM;
        float r[8];
        #pragma unroll
        for (int j = 0; j < 8; ++j) { float v = row[j]; r[j] = rnd(v * v); }
        #pragma unroll
        for (int m = 1; m < 8; ++m)
            #pragma unroll
            for (int j = 0; j < 8; ++j) { float v = row[8 * m + j]; r[j] += rnd(v * v); }
        e2[k] = ((r[0] + r[1]) + (r[2] + r[3])) + ((r[4] + r[5]) + (r[6] + r[7]));
    } else if (gid < 12800) {
        int pid = gid - 4608;            // 8192 entries
        int kk = pid >> 10, c4 = (pid >> 6) & 15, lane = pid & 63;
        int code = lane * 8 + kk;
        P4[pid] = *(const float4*)(emb + code * DDIM + c4 * 4);
    }
}

// -------------------- fused distance/argmin + epilogue kernel --------------------
// 512 thr = 8 waves x 16 px = 128 px/block. Grid 512 -> 2 blocks/CU, all resident.
// Full 64 KB bf16 codebook staged into LDS ONCE via global_load_lds DMA. Two
// barriers per block. Inner-loop min/2nd-min via v_med3_f32: 5 VALU/eval vs 7-8
// (R9 counter evidence: VALUBusy 45% -> select chain is the dominant VALU cost).
__global__ __launch_bounds__(512, 4) void k_dist(
        const float* __restrict__ z_e, const float* __restrict__ emb,
        const bf16x8* __restrict__ Bh, const float* __restrict__ e2g,
        int* __restrict__ idx, int* __restrict__ glist, int* __restrict__ nflag,
        int* __restrict__ counts, float* __restrict__ slots,
        float* __restrict__ out) {
    __shared__ bf16x8 Bs[4096];      // 64 KB: full codebook, fragment order
    __shared__ float e2s[512];
    __shared__ int   hist[512];
    __shared__ int   flist[128];
    __shared__ int   fcnt, fbase;

    int t = threadIdx.x;
    int pxbase = blockIdx.x * 128;
    int batch = pxbase >> 12;
    int p0 = pxbase & 4095;
    const float* zb = z_e + (size_t)batch * (CH * HW) + p0;

    // B-stage: fire 8 async 16B DMAs (in flight during A-loads below)
    #pragma unroll
    for (int i = 0; i < 8; ++i) gl_lds16(Bh + i * 512 + t, Bs + i * 512 + t);

    hist[t] = 0;
    e2s[t] = e2g[t];
    if (t == 0) fcnt = 0;

    int w = t >> 6, lane = t & 63, col = lane & 15, quad = lane >> 4;
    int px = w * 16 + col;

    // A-frags direct from global: px = w*16+col, k = chunk*32 + quad*8 + j
    bf16x8 a0, a1;
    #pragma unroll
    for (int j = 0; j < 8; ++j) {
        a0[j] = f2bf(zb[(quad * 8 + j) * HW + px]);
        a1[j] = f2bf(zb[(32 + quad * 8 + j) * HW + px]);
    }
    __syncthreads();   // barrier #1 (drains the DMA vmcnt)

    float m1[4], m2[4];
    int   i1[4];
    #pragma unroll
    for (int r = 0; r < 4; ++r) { m1[r] = 1e30f; m2[r] = 1e30f; i1[r] = 0; }

    // barrier-free N loop: pure ds_read_b128 + MFMA + med3-select
    #pragma unroll 4
    for (int tn = 0; tn < 32; ++tn) {
        bf16x8 c0 = Bs[tn * 128 + lane];
        bf16x8 c1 = Bs[tn * 128 + 64 + lane];
        float e2v = e2s[tn * 16 + col];
        int n = tn * 16 + col;
        f32x4 acc = {0.f, 0.f, 0.f, 0.f};
        acc = __builtin_amdgcn_mfma_f32_16x16x32_bf16(a0, c0, acc, 0, 0, 0);
        acc = __builtin_amdgcn_mfma_f32_16x16x32_bf16(a1, c1, acc, 0, 0, 0);
        #pragma unroll
        for (int r = 0; r < 4; ++r) {
            float d = fmaf(-2.0f, acc[r], e2v);
            // m2' = med3(d,m1,m2): d<m1 -> m1 | m1<=d<m2 -> d | else m2  (2nd-min)
            m2[r] = __builtin_amdgcn_fmed3f(d, m1[r], m2[r]);
            bool c = d < m1[r];
            m1[r] = fminf(d, m1[r]);
            i1[r] = c ? n : i1[r];   // tie (d==m1) keeps earlier n = np first-occurrence
        }
    }

    // merge the 16 cols (xor butterfly -> every lane holds result for px quad*4+r)
    #pragma unroll
    for (int off = 1; off < 16; off <<= 1) {
        #pragma unroll
        for (int r = 0; r < 4; ++r) {
            float om1 = __shfl_xor(m1[r], off);
            float om2 = __shfl_xor(m2[r], off);
            int   oi  = __shfl_xor(i1[r], off);
            if (om1 < m1[r] || (om1 == m1[r] && oi < i1[r])) {
                m2[r] = fminf(m1[r], om2);
                m1[r] = om1;
                i1[r] = oi;
            } else {
                m2[r] = fminf(m2[r], om1);
            }
        }
    }

    // per-pixel outputs: idx, out-idx, LDS histogram + LDS flag list (no global atomics)
    if (col == 0) {
        #pragma unroll
        for (int r = 0; r < 4; ++r) {
            int g = pxbase + w * 16 + quad * 4 + r;
            idx[g] = i1[r];
            out[OUT_IDX + g] = (float)i1[r];
            atomicAdd(&hist[i1[r]], 1);
            if (m2[r] - m1[r] < MARGIN) {
                int pos = atomicAdd(&fcnt, 1);   // LDS atomic
                flist[pos] = g;
            }
        }
    }

    // fused epilogue: z_q_st for this wave's 16 px (z_e is L1/L3-hot), + loss partial
    int q4 = lane & 3;
    int bidx[4];
    #pragma unroll
    for (int j = 0; j < 4; ++j) bidx[j] = __shfl(i1[j], q4 << 4);  // best for px q4*4+j
    const float* zw = zb + w * 16;
    float* ow = out + (size_t)batch * (CH * HW) + p0 + w * 16;
    float lsum = 0.0f;
    #pragma unroll
    for (int it = 0; it < 4; ++it) {
        int c = it * 16 + (lane >> 2);
        float4 ze = *(const float4*)(zw + c * HW + q4 * 4);
        float d0 = emb[bidx[0] * DDIM + c] - ze.x;
        float d1 = emb[bidx[1] * DDIM + c] - ze.y;
        float d2 = emb[bidx[2] * DDIM + c] - ze.z;
        float d3 = emb[bidx[3] * DDIM + c] - ze.w;
        float4 o = {ze.x + d0, ze.y + d1, ze.z + d2, ze.w + d3};
        *(float4*)(ow + c * HW + q4 * 4) = o;
        lsum = lsum + d0 * d0 + d1 * d1 + d2 * d2 + d3 * d3;
    }
    #pragma unroll
    for (int off = 32; off; off >>= 1) lsum += __shfl_down(lsum, off);
    if (lane == 0) atomicAdd(&slots[((blockIdx.x * 8 + w) & 63) * 16], lsum);

    // barrier #2, then flush histogram + flag list (one returning atomic per block)
    __syncthreads();
    int v0 = hist[t];
    if (v0) atomicAdd(&counts[t], v0);
    if (t == 0) fbase = atomicAdd(nflag, fcnt);
    __syncthreads();
    if (t < fcnt) glist[fbase + t] = flist[t];
}

// -------------------- refine: full codebook in LDS, numpy-fp32-exact re-argmin ------
// Full 128 KB fp32 transposed codebook staged ONCE per block via global_load_lds
// (R12 lesson: streaming it per-flag from L2 = 268 MB fetch = 350 us). One barrier,
// then each wave grid-strides flags barrier-free. Numerics identical to the
// R9-R13-verified path.  __launch_bounds__(256) is LOAD-BEARING (R5: VGPR cap 64
// -> spill -> 90 MB scratch traffic).
__global__ __launch_bounds__(256) void k_refine(
        const float* __restrict__ z_e, const float* __restrict__ emb,
        const float* __restrict__ e2, const float4* __restrict__ P4,
        const int* __restrict__ glist, const int* __restrict__ nflag,
        int* __restrict__ idx, int* __restrict__ counts,
        float* __restrict__ slots, float* __restrict__ out) {
    __shared__ float4 Ps[8192];      // 128 KB: full transposed codebook
    __shared__ float  xs[4][64];     // one x-vector slot per wave

    int t = threadIdx.x;
    int w = t >> 6, lane = t & 63;
    int n = nflag[0];
    if (blockIdx.x >= n) return;     // block-uniform early exit (handles n==0)

    #pragma unroll
    for (int i = 0; i < 32; ++i) gl_lds16(P4 + i * 256 + t, Ps + i * 256 + t);
    __syncthreads();                 // the only barrier (drains DMA)

    // per-lane e2 for codes lane*8..+7 (coalesced float4 pair)
    float4 ea = ((const float4*)e2)[lane * 2];
    float4 eb = ((const float4*)e2)[lane * 2 + 1];
    float e2v[8] = {ea.x, ea.y, ea.z, ea.w, eb.x, eb.y, eb.z, eb.w};

    int wid = blockIdx.x * 4 + w;
    for (int j = wid; j < n; j += 1024) {
        int g = glist[j];                 // wave-uniform scalar load
        int b = g >> 12, p = g & 4095;
        xs[w][lane] = z_e[(size_t)b * (CH * HW) + (size_t)lane * HW + p];
        __threadfence_block();            // wave-lockstep LDS visibility

        const float* xr = xs[w];
        // numpy pairwise ||x||^2 (8 accumulators + tree), broadcast LDS reads
        float r[8];
        #pragma unroll
        for (int jj = 0; jj < 8; ++jj) { float v = xr[jj]; r[jj] = rnd(v * v); }
        #pragma unroll
        for (int mm = 1; mm < 8; ++mm)
            #pragma unroll
            for (int jj = 0; jj < 8; ++jj) { float v = xr[8 * mm + jj]; r[jj] += rnd(v * v); }
        float x2 = ((r[0] + r[1]) + (r[2] + r[3])) + ((r[4] + r[5]) + (r[6] + r[7]));

        float bestd = INFINITY;
        int besti = 1 << 30;
        #pragma unroll
        for (int kk = 0; kk < 8; ++kk) {
            double d0 = 0.0, d1 = 0.0, d2 = 0.0, d3 = 0.0;
            #pragma unroll
            for (int c4 = 0; c4 < 16; ++c4) {
                float4 xq = *(const float4*)&xr[c4 * 4];         // broadcast
                float4 ev = Ps[(kk * 16 + c4) * 64 + lane];      // per-lane, conflict-free
                d0 = fma((double)xq.x, (double)ev.x, d0);
                d1 = fma((double)xq.y, (double)ev.y, d1);
                d2 = fma((double)xq.z, (double)ev.z, d2);
                d3 = fma((double)xq.w, (double)ev.w, d3);
            }
            float dotf = (float)((d0 + d1) + (d2 + d3));  // ~= sgemm dot
            float tt = x2 + e2v[kk];                      // np fp32 add
            float d = tt - 2.0f * dotf;                   // np fp32 sub
            if (d < bestd) { bestd = d; besti = lane * 8 + kk; }
        }
        #pragma unroll
        for (int off = 32; off; off >>= 1) {
            float od = __shfl_down(bestd, off);
            int   oi = __shfl_down(besti, off);
            if (od < bestd || (od == bestd && oi < besti)) { bestd = od; besti = oi; }
        }
        besti = __shfl(besti, 0);

        int old = idx[g];
        if (besti != old) {
            // patch z_q_st row (lane c = channel c), loss delta, counts, index
            float xc = xr[lane];
            float qn = emb[besti * DDIM + lane];
            float qo = emb[old * DDIM + lane];
            float dn = qn - xc, dold = qo - xc;
            out[(size_t)b * (CH * HW) + (size_t)lane * HW + p] = xc + dn;
            float delta = dn * dn - dold * dold;
            #pragma unroll
            for (int off = 32; off; off >>= 1) delta += __shfl_down(delta, off);
            if (lane == 0) {
                atomicAdd(&slots[(wid & 63) * 16], delta);
                atomicAdd(&counts[old], -1);
                atomicAdd(&counts[besti], 1);
                idx[g] = besti;
                out[OUT_IDX + g] = (float)besti;
            }
        }
    }
}

// -------------------- final scalars: loss, perplexity --------------------
__global__ void k_final(const int* __restrict__ counts,
                        const float* __restrict__ slots,
                        float* __restrict__ out) {
    int t = threadIdx.x;  // 512 threads, 1 block
    float cnt = (float)counts[t];
    float pb = cnt * (1.0f / 65536.0f);
    float term = pb * logf(pb + 1e-10f);
    #pragma unroll
    for (int off = 32; off; off >>= 1) term += __shfl_down(term, off);
    __shared__ float ls[8];
    __shared__ float lsum;
    int lane = t & 63, w = t >> 6;
    if (lane == 0) ls[w] = term;
    if (w == 0) {                               // wave 0 reduces the 64 loss slots
        float s2 = slots[lane * 16];
        #pragma unroll
        for (int off = 32; off; off >>= 1) s2 += __shfl_down(s2, off);
        if (lane == 0) lsum = s2;
    }
    __syncthreads();
    if (t == 0) {
        float s = 0.0f;
        #pragma unroll
        for (int i = 0; i < 8; ++i) s += ls[i];
        out[OUT_PPL]  = expf(-s);
        out[OUT_LOSS] = 0.25f * (lsum / (float)NELEM);
    }
}

extern "C" void kernel_launch(void* const* d_in, const int* in_sizes, int n_in,
                              void* d_out, int out_size, void* d_ws, size_t ws_size,
                              hipStream_t stream) {
    const float* z_e = (const float*)d_in[0];
    const float* emb = (const float*)d_in[1];
    float* out = (float*)d_out;
    char* ws = (char*)d_ws;

    // ws layout
    int*    idx    = (int*)(ws);              // 65536 ints   [0, 262144)
    int*    glist  = (int*)(ws + 262144);     // 65536 ints   [262144, 524288)
    float*  e2     = (float*)(ws + 524288);   // 512 floats   [524288, 526336)
    int*    nflag  = (int*)(ws + 526336);     // 1 int (+pad) [526336, 526400)
    int*    counts = (int*)(ws + 526400);     // 512 ints     [526400, 528448)
    float*  slots  = (float*)(ws + 528448);   // 64 x 16 floats [528448, 532544)
    bf16x8* Bh     = (bf16x8*)(ws + 532544);  // 4096 x 16 B = 64 KB
    float4* P4     = (float4*)(ws + 598080);  // 8192 x 16 B = 128 KB [598080, 729152)

    // zero nflag + counts + slots (ws is poisoned 0xAA before every timed launch)
    hipMemsetAsync(ws + 526336, 0, 532544 - 526336, stream);

    k_prep<<<50, 256, 0, stream>>>(emb, e2, Bh, P4);
    k_dist<<<NPIX / 128, 512, 0, stream>>>(z_e, emb, Bh, e2, idx, glist, nflag, counts, slots, out);
    k_refine<<<256, 256, 0, stream>>>(z_e, emb, e2, P4, glist, nflag, idx, counts, slots, out);
    k_final<<<1, 512, 0, stream>>>(counts, slots, out);
}